// Round 1
// baseline (345.884 us; speedup 1.0000x reference)
//
#include <hip/hip_runtime.h>
#include <hip/hip_bf16.h>

// Problem constants (match reference):
//   B=2048, S=32, H=256, NSEG=B*S=65536, NNBR=524288
#define BB    2048
#define SS    32
#define HH    256
#define NSEGC 65536
#define NNBRC 524288

// ---------------------------------------------------------------------------
// Kernel 1: per-segment lower_bound over sorted segment_ids -> start[NSEG+1]
// ---------------------------------------------------------------------------
__global__ __launch_bounds__(256) void seg_bounds_kernel(
    const int* __restrict__ segment_ids,
    int* __restrict__ start)
{
    const int seg = blockIdx.x * blockDim.x + threadIdx.x;
    if (seg > NSEGC) return;
    int lo = 0, hi = NNBRC;
    while (lo < hi) {
        const int mid = (lo + hi) >> 1;
        if (segment_ids[mid] < seg) lo = mid + 1;
        else hi = mid;
    }
    start[seg] = lo;
}

// ---------------------------------------------------------------------------
// Kernel 2: one 64-lane wave per segment. lane*4 floats = one float4 of the
// H=256 row. Gather-accumulate neighbor rows, write mean + ent row + rel row.
// ---------------------------------------------------------------------------
__global__ __launch_bounds__(256) void agg_kernel(
    const int*   __restrict__ neighbor_idx,
    const int*   __restrict__ s_tem,
    const int*   __restrict__ r_tem,
    const float* __restrict__ ent,
    const float* __restrict__ rel,
    const int*   __restrict__ start,
    float*       __restrict__ out)
{
    const int wave = (blockIdx.x * blockDim.x + threadIdx.x) >> 6;
    const int lane = threadIdx.x & 63;
    if (wave >= NSEGC) return;
    const int seg = wave;
    const int b   = seg >> 5;           // seg / S

    const int begin = start[seg];
    const int end   = start[seg + 1];

    float ax = 0.f, ay = 0.f, az = 0.f, aw = 0.f;

    for (int base = begin; base < end; base += 64) {
        const int cnt = min(64, end - base);
        int myidx = 0;
        if (lane < cnt) myidx = neighbor_idx[base + lane];
        #pragma unroll 4
        for (int j = 0; j < cnt; ++j) {
            const int nbr = __shfl(myidx, j);
            const float4 v = *reinterpret_cast<const float4*>(
                ent + (size_t)nbr * HH + lane * 4);
            ax += v.x; ay += v.y; az += v.z; aw += v.w;
        }
    }

    const float inv = 1.0f / fmaxf((float)(end - begin), 1.0f);
    float4 m;
    m.x = ax * inv; m.y = ay * inv; m.z = az * inv; m.w = aw * inv;

    float* o = out + (size_t)seg * (3 * HH);
    *reinterpret_cast<float4*>(o + lane * 4) = m;

    const int e = s_tem[b];
    const float4 ev = *reinterpret_cast<const float4*>(
        ent + (size_t)e * HH + lane * 4);
    *reinterpret_cast<float4*>(o + HH + lane * 4) = ev;

    const int r = r_tem[b];
    const float4 rv = *reinterpret_cast<const float4*>(
        rel + (size_t)r * HH + lane * 4);
    *reinterpret_cast<float4*>(o + 2 * HH + lane * 4) = rv;
}

// ---------------------------------------------------------------------------
// Kernel 3: s_hist_dt -> tail of output (pure float4 copy, 65536 floats)
// ---------------------------------------------------------------------------
__global__ __launch_bounds__(256) void dt_copy_kernel(
    const float* __restrict__ dt,
    float* __restrict__ out_tail)
{
    const int i = blockIdx.x * blockDim.x + threadIdx.x;   // 16384 float4s
    reinterpret_cast<float4*>(out_tail)[i] =
        reinterpret_cast<const float4*>(dt)[i];
}

// ---------------------------------------------------------------------------
extern "C" void kernel_launch(void* const* d_in, const int* in_sizes, int n_in,
                              void* d_out, int out_size, void* d_ws, size_t ws_size,
                              hipStream_t stream) {
    const int*   neighbor_idx = (const int*)  d_in[0];
    const int*   segment_ids  = (const int*)  d_in[1];
    const int*   s_tem        = (const int*)  d_in[2];
    const int*   r_tem        = (const int*)  d_in[3];
    const float* s_hist_dt    = (const float*)d_in[4];
    const float* ent_embeds   = (const float*)d_in[5];
    const float* rel_embeds   = (const float*)d_in[6];
    float*       out          = (float*)d_out;

    int* start = (int*)d_ws;   // (NSEG+1) ints = 262148 bytes of scratch

    // Kernel 1: segment boundaries (NSEG+1 threads)
    {
        const int threads = 256;
        const int total   = NSEGC + 1;
        const int blocks  = (total + threads - 1) / threads;
        seg_bounds_kernel<<<blocks, threads, 0, stream>>>(segment_ids, start);
    }

    // Kernel 2: one wave per segment; 4 waves per 256-thread block
    {
        const int threads = 256;
        const int blocks  = NSEGC / 4;   // 16384
        agg_kernel<<<blocks, threads, 0, stream>>>(
            neighbor_idx, s_tem, r_tem, ent_embeds, rel_embeds, start, out);
    }

    // Kernel 3: dt tail copy (65536 floats = 16384 float4)
    {
        float* out_tail = out + (size_t)NSEGC * (3 * HH);
        dt_copy_kernel<<<64, 256, 0, stream>>>(s_hist_dt, out_tail);
    }
}

// Round 3
// 338.802 us; speedup vs baseline: 1.0209x; 1.0209x over previous
//
#include <hip/hip_runtime.h>
#include <hip/hip_bf16.h>

// Problem constants (match reference):
//   B=2048, S=32, H=256, NSEG=B*S=65536, NNBR=524288
#define BB    2048
#define SS    32
#define HH    256
#define NSEGC 65536
#define NNBRC 524288
#define NXCD  8

// clang ext-vector: accepted by __builtin_nontemporal_store (HIP float4 is not)
using f32x4 = __attribute__((ext_vector_type(4))) float;

// ---------------------------------------------------------------------------
// Kernel 1: per-segment lower_bound over sorted segment_ids -> start[NSEG+1]
//           + folded-in float4 copy of s_hist_dt into the output tail.
// ---------------------------------------------------------------------------
__global__ __launch_bounds__(256) void seg_bounds_dt_kernel(
    const int*   __restrict__ segment_ids,
    int*         __restrict__ start,
    const float* __restrict__ dt,
    float*       __restrict__ out_tail)
{
    const int i = blockIdx.x * blockDim.x + threadIdx.x;

    // dt tail copy: 65536 floats = 16384 float4s (nontemporal: no reuse)
    if (i < NSEGC / 4) {
        const f32x4 v = reinterpret_cast<const f32x4*>(dt)[i];
        __builtin_nontemporal_store(v, reinterpret_cast<f32x4*>(out_tail) + i);
    }

    if (i > NSEGC) return;
    int lo = 0, hi = NNBRC;
    while (lo < hi) {
        const int mid = (lo + hi) >> 1;
        if (segment_ids[mid] < i) lo = mid + 1;
        else hi = mid;
    }
    start[i] = lo;
}

// ---------------------------------------------------------------------------
// Kernel 2: one 64-lane wave per segment. lane*4 floats = one float4 of the
// H=256 row. Gather-accumulate neighbor rows, write mean + ent row + rel row.
// All output stores are NON-TEMPORAL so the 201 MB output stream does not
// write-allocate and evict the L3-resident 102 MB ent_embeds table.
// XCD-chunked block swizzle keeps the 8 blocks of one batch `b` on one XCD.
// ---------------------------------------------------------------------------
__global__ __launch_bounds__(256) void agg_kernel(
    const int*   __restrict__ neighbor_idx,
    const int*   __restrict__ s_tem,
    const int*   __restrict__ r_tem,
    const float* __restrict__ ent,
    const float* __restrict__ rel,
    const int*   __restrict__ start,
    float*       __restrict__ out)
{
    // chunked XCD swizzle: HW assigns consecutive blockIdx round-robin to the
    // 8 XCDs; remap so each XCD owns a contiguous chunk of segments.
    const int chunk = gridDim.x / NXCD;                       // 2048
    const int wg    = (blockIdx.x % NXCD) * chunk + blockIdx.x / NXCD;

    const int seg  = wg * 4 + (threadIdx.x >> 6);
    const int lane = threadIdx.x & 63;
    if (seg >= NSEGC) return;
    const int b = seg >> 5;            // seg / S

    const int begin = start[seg];
    const int end   = start[seg + 1];

    float ax = 0.f, ay = 0.f, az = 0.f, aw = 0.f;

    for (int base = begin; base < end; base += 64) {
        const int cnt = min(64, end - base);
        int myidx = 0;
        if (lane < cnt) myidx = neighbor_idx[base + lane];
        #pragma unroll 4
        for (int j = 0; j < cnt; ++j) {
            const int nbr = __shfl(myidx, j);
            const f32x4 v = *reinterpret_cast<const f32x4*>(
                ent + (size_t)nbr * HH + lane * 4);
            ax += v.x; ay += v.y; az += v.z; aw += v.w;
        }
    }

    const float inv = 1.0f / fmaxf((float)(end - begin), 1.0f);
    f32x4 m;
    m.x = ax * inv; m.y = ay * inv; m.z = az * inv; m.w = aw * inv;

    float* o = out + (size_t)seg * (3 * HH);
    __builtin_nontemporal_store(m, reinterpret_cast<f32x4*>(o) + lane);

    const int e = s_tem[b];
    const f32x4 ev = *reinterpret_cast<const f32x4*>(
        ent + (size_t)e * HH + lane * 4);
    __builtin_nontemporal_store(ev, reinterpret_cast<f32x4*>(o + HH) + lane);

    const int r = r_tem[b];
    const f32x4 rv = *reinterpret_cast<const f32x4*>(
        rel + (size_t)r * HH + lane * 4);
    __builtin_nontemporal_store(rv, reinterpret_cast<f32x4*>(o + 2 * HH) + lane);
}

// ---------------------------------------------------------------------------
extern "C" void kernel_launch(void* const* d_in, const int* in_sizes, int n_in,
                              void* d_out, int out_size, void* d_ws, size_t ws_size,
                              hipStream_t stream) {
    const int*   neighbor_idx = (const int*)  d_in[0];
    const int*   segment_ids  = (const int*)  d_in[1];
    const int*   s_tem        = (const int*)  d_in[2];
    const int*   r_tem        = (const int*)  d_in[3];
    const float* s_hist_dt    = (const float*)d_in[4];
    const float* ent_embeds   = (const float*)d_in[5];
    const float* rel_embeds   = (const float*)d_in[6];
    float*       out          = (float*)d_out;

    int* start = (int*)d_ws;   // (NSEG+1) ints = 262148 bytes of scratch

    // Kernel 1: segment boundaries (NSEG+1 threads) + dt tail copy
    {
        const int threads = 256;
        const int total   = NSEGC + 1;
        const int blocks  = (total + threads - 1) / threads;   // 257
        float* out_tail = out + (size_t)NSEGC * (3 * HH);
        seg_bounds_dt_kernel<<<blocks, threads, 0, stream>>>(
            segment_ids, start, s_hist_dt, out_tail);
    }

    // Kernel 2: one wave per segment; 4 waves per 256-thread block
    {
        const int threads = 256;
        const int blocks  = NSEGC / 4;   // 16384 (divisible by 8 for swizzle)
        agg_kernel<<<blocks, threads, 0, stream>>>(
            neighbor_idx, s_tem, r_tem, ent_embeds, rel_embeds, start, out);
    }
}

// Round 5
// 336.648 us; speedup vs baseline: 1.0274x; 1.0064x over previous
//
#include <hip/hip_runtime.h>
#include <hip/hip_bf16.h>

// Problem constants: B=2048, S=32, H=256, NSEG=65536, NNBR=524288
#define BB    2048
#define SS    32
#define HH    256
#define NSEGC 65536
#define NNBRC 524288
#define NXCD  8
#define SPW   4          // segments per wave (consecutive -> contiguous idx range)

using f32x4 = __attribute__((ext_vector_type(4))) float;

// ---------------------------------------------------------------------------
// Kernel 1: per-segment lower_bound over sorted segment_ids -> start[NSEG+1]
//           + folded-in float4 copy of s_hist_dt into the output tail.
// ---------------------------------------------------------------------------
__global__ __launch_bounds__(256) void seg_bounds_dt_kernel(
    const int*   __restrict__ segment_ids,
    int*         __restrict__ start,
    const float* __restrict__ dt,
    float*       __restrict__ out_tail)
{
    const int i = blockIdx.x * blockDim.x + threadIdx.x;

    if (i < NSEGC / 4) {
        const f32x4 v = reinterpret_cast<const f32x4*>(dt)[i];
        __builtin_nontemporal_store(v, reinterpret_cast<f32x4*>(out_tail) + i);
    }

    if (i > NSEGC) return;
    int lo = 0, hi = NNBRC;
    while (lo < hi) {
        const int mid = (lo + hi) >> 1;
        if (segment_ids[mid] < i) lo = mid + 1;
        else hi = mid;
    }
    start[i] = lo;
}

// ---------------------------------------------------------------------------
// Kernel 2: one wave handles 4 consecutive segments. Their neighbor ranges
// are contiguous, so one coalesced idx load feeds ~32 gathers; 8 independent
// 1KB row-gathers in flight per batch; bucket-select accumulation into 4
// named accumulators via scalar (readfirstlane) boundaries. NT stores.
// ---------------------------------------------------------------------------
__global__ __launch_bounds__(256) void agg_kernel(
    const int*   __restrict__ neighbor_idx,
    const int*   __restrict__ s_tem,
    const int*   __restrict__ r_tem,
    const float* __restrict__ ent,
    const float* __restrict__ rel,
    const int*   __restrict__ start,
    float*       __restrict__ out)
{
    // chunked XCD swizzle
    const int chunkw = gridDim.x / NXCD;
    const int wg   = (blockIdx.x % NXCD) * chunkw + blockIdx.x / NXCD;
    const int wave = wg * 4 + (threadIdx.x >> 6);      // 0..16383
    const int lane = threadIdx.x & 63;
    const int seg0 = wave * SPW;
    const int b    = seg0 >> 5;                        // seg0 / S

    // 5 boundaries start[seg0..seg0+4] via one lane-load, hoisted to SGPRs
    const int sv = start[seg0 + min(lane, SPW)];
    const int p0 = __builtin_amdgcn_readfirstlane(__shfl(sv, 0));
    const int p1 = __builtin_amdgcn_readfirstlane(__shfl(sv, 1));
    const int p2 = __builtin_amdgcn_readfirstlane(__shfl(sv, 2));
    const int p3 = __builtin_amdgcn_readfirstlane(__shfl(sv, 3));
    const int p4 = __builtin_amdgcn_readfirstlane(__shfl(sv, 4));
    const int total = p4 - p0;
    const int r1 = p1 - p0, r2 = p2 - p0, r3 = p3 - p0;

    // broadcast subject/relation rows (one load for 4 output rows; L2-hot)
    const int e = s_tem[b];
    const int r = r_tem[b];
    const f32x4 ev = *reinterpret_cast<const f32x4*>(ent + (size_t)e * HH + lane * 4);
    const f32x4 rv = *reinterpret_cast<const f32x4*>(rel + (size_t)r * HH + lane * 4);

    f32x4 a0 = {0.f,0.f,0.f,0.f}, a1 = a0, a2 = a0, a3 = a0;

    for (int base = 0; base < total; base += 64) {
        const int cnt = min(64, total - base);
        int myidx = 0;
        if (lane < cnt) myidx = neighbor_idx[p0 + base + lane];

        for (int j = 0; j < cnt; j += 8) {
            const int m = min(8, cnt - j);   // uniform scalar

            // issue up to 8 independent 1KB row gathers
#define GLD(K, VK)                                                         \
            f32x4 VK = {0.f,0.f,0.f,0.f};                                  \
            if (K < m) {                                                   \
                const int nb = __shfl(myidx, j + K);                       \
                VK = *reinterpret_cast<const f32x4*>(                      \
                    ent + (size_t)nb * HH + lane * 4);                     \
            }
            GLD(0, v0) GLD(1, v1) GLD(2, v2) GLD(3, v3)
            GLD(4, v4) GLD(5, v5) GLD(6, v6) GLD(7, v7)
#undef GLD

            // bucket-select accumulate (uniform scalar branches)
#define ACC(K, VK)                                                         \
            if (K < m) {                                                   \
                const int p = base + j + K;                                \
                if      (p < r1) a0 += VK;                                 \
                else if (p < r2) a1 += VK;                                 \
                else if (p < r3) a2 += VK;                                 \
                else             a3 += VK;                                 \
            }
            ACC(0, v0) ACC(1, v1) ACC(2, v2) ACC(3, v3)
            ACC(4, v4) ACC(5, v5) ACC(6, v6) ACC(7, v7)
#undef ACC
        }
    }

    const float i0 = 1.0f / fmaxf((float)(p1 - p0), 1.0f);
    const float i1 = 1.0f / fmaxf((float)(p2 - p1), 1.0f);
    const float i2 = 1.0f / fmaxf((float)(p3 - p2), 1.0f);
    const float i3 = 1.0f / fmaxf((float)(p4 - p3), 1.0f);

    float* o = out + (size_t)seg0 * (3 * HH);
#define STROW(S, AV, INV)                                                  \
    {                                                                      \
        const f32x4 mm = AV * INV;                                         \
        float* os = o + (size_t)(S) * (3 * HH);                            \
        __builtin_nontemporal_store(mm, reinterpret_cast<f32x4*>(os) + lane);          \
        __builtin_nontemporal_store(ev, reinterpret_cast<f32x4*>(os + HH) + lane);     \
        __builtin_nontemporal_store(rv, reinterpret_cast<f32x4*>(os + 2 * HH) + lane); \
    }
    STROW(0, a0, i0) STROW(1, a1, i1) STROW(2, a2, i2) STROW(3, a3, i3)
#undef STROW
}

// ---------------------------------------------------------------------------
extern "C" void kernel_launch(void* const* d_in, const int* in_sizes, int n_in,
                              void* d_out, int out_size, void* d_ws, size_t ws_size,
                              hipStream_t stream) {
    const int*   neighbor_idx = (const int*)  d_in[0];
    const int*   segment_ids  = (const int*)  d_in[1];
    const int*   s_tem        = (const int*)  d_in[2];
    const int*   r_tem        = (const int*)  d_in[3];
    const float* s_hist_dt    = (const float*)d_in[4];
    const float* ent_embeds   = (const float*)d_in[5];
    const float* rel_embeds   = (const float*)d_in[6];
    float*       out          = (float*)d_out;

    int* start = (int*)d_ws;   // (NSEG+1) ints of scratch

    // Kernel 1: segment boundaries + dt tail copy
    {
        const int threads = 256;
        const int blocks  = (NSEGC + 1 + threads - 1) / threads;   // 257
        float* out_tail = out + (size_t)NSEGC * (3 * HH);
        seg_bounds_dt_kernel<<<blocks, threads, 0, stream>>>(
            segment_ids, start, s_hist_dt, out_tail);
    }

    // Kernel 2: 4 segments per wave; 4 waves per block -> 4096 blocks
    {
        const int threads = 256;
        const int blocks  = NSEGC / SPW / 4;   // 4096 (divisible by 8)
        agg_kernel<<<blocks, threads, 0, stream>>>(
            neighbor_idx, s_tem, r_tem, ent_embeds, rel_embeds, start, out);
    }
}